// Round 4
// baseline (670.961 us; speedup 1.0000x reference)
//
#include <hip/hip_runtime.h>

#define LOG2E 1.4426950408889634f

typedef __attribute__((ext_vector_type(8))) short short8;
typedef __attribute__((ext_vector_type(4))) float f32x4;

__device__ inline unsigned short f2bf(float f) {
  unsigned u = __float_as_uint(f);
  u += 0x7fffu + ((u >> 16) & 1u);
  return (unsigned short)(u >> 16);
}

#define MFMA16(a, b, c) __builtin_amdgcn_mfma_f32_16x16x32_bf16((a), (b), (c), 0, 0, 0)

#define GLDS16(gp, lp)                                                              \
  __builtin_amdgcn_global_load_lds((const __attribute__((address_space(1))) void*)(gp), \
                                   (__attribute__((address_space(3))) void*)(lp), 16, 0, 0)

__device__ inline f32x4 zero4() {
  f32x4 z = {0.f, 0.f, 0.f, 0.f};
  return z;
}

__device__ inline int swz8(int row) { return (row ^ (row >> 3)) & 7; }

// ---------------------------------------------------------------- merged cast fp32 -> bf16 (all 6 arrays, 1 dispatch)
__global__ __launch_bounds__(256) void k_cast6(
    const float* __restrict__ e, const float* __restrict__ q, const float* __restrict__ wq,
    const float* __restrict__ wo, const float* __restrict__ wb, const float* __restrict__ wa,
    unsigned short* __restrict__ eo, unsigned short* __restrict__ qo, unsigned short* __restrict__ wqo,
    unsigned short* __restrict__ woo, unsigned short* __restrict__ wbo, unsigned short* __restrict__ wao) {
  int i = (blockIdx.x * 256 + threadIdx.x) * 4;
  const float* src;
  unsigned short* dst;
  int off;
  if (i < 16777216) { src = e; dst = eo; off = i; }
  else if (i < 25165824) { src = q; dst = qo; off = i - 16777216; }
  else if (i < 26214400) { src = wq; dst = wqo; off = i - 25165824; }
  else if (i < 27262976) { src = wo; dst = woo; off = i - 26214400; }
  else if (i < 27787264) { src = wb; dst = wbo; off = i - 27262976; }
  else { src = wa; dst = wao; off = i - 27787264; }
  float4 v = *(const float4*)(src + off);
  unsigned lo = (unsigned)f2bf(v.x) | ((unsigned)f2bf(v.y) << 16);
  unsigned hi = (unsigned)f2bf(v.z) | ((unsigned)f2bf(v.w) << 16);
  *(uint2*)(dst + off) = make_uint2(lo, hi);
}

// ---------------------------------------------------------------- K1: q = query @ Wq^T (scaled by log2e/8), -> (B,H,SQ,64) bf16
__global__ __launch_bounds__(256, 2) void k_qproj(const unsigned short* __restrict__ A,
                                                  const unsigned short* __restrict__ Bw,
                                                  unsigned short* __restrict__ Qout) {
  __shared__ __align__(16) short As[128 * 32];
  __shared__ __align__(16) short Bs[128 * 32];
  const int K = 1024;
  int tid = threadIdx.x;
  int w = tid >> 6, lane = tid & 63, quad = lane >> 4, c = lane & 15;
  int m0 = blockIdx.x * 128, n0 = blockIdx.y * 128;
  int wm = (w >> 1) * 64, wn = (w & 1) * 64;
  f32x4 acc[4][4];
#pragma unroll
  for (int i = 0; i < 4; i++)
#pragma unroll
    for (int j = 0; j < 4; j++) acc[i][j] = zero4();

  for (int k0 = 0; k0 < K; k0 += 32) {
#pragma unroll
    for (int i = 0; i < 2; i++) {
      int seg = w * 2 + i;
      int bo = seg * 1024 + lane * 16;
      int row = bo >> 6, col = (bo & 63) >> 1;
      GLDS16(A + (size_t)(m0 + row) * K + k0 + col, (char*)As + seg * 1024);
      GLDS16(Bw + (size_t)(n0 + row) * K + k0 + col, (char*)Bs + seg * 1024);
    }
    __syncthreads();
    short8 af[4], bfr[4];
#pragma unroll
    for (int i = 0; i < 4; i++) {
      af[i] = *(const short8*)&As[(wm + i * 16 + c) * 32 + quad * 8];
      bfr[i] = *(const short8*)&Bs[(wn + i * 16 + c) * 32 + quad * 8];
    }
#pragma unroll
    for (int mi = 0; mi < 4; mi++)
#pragma unroll
      for (int ni = 0; ni < 4; ni++) acc[mi][ni] = MFMA16(af[mi], bfr[ni], acc[mi][ni]);
    __syncthreads();
  }
  const float scale = 0.125f * LOG2E;
#pragma unroll
  for (int mi = 0; mi < 4; mi++) {
    int rowb = m0 + wm + mi * 16 + quad * 4;
#pragma unroll
    for (int ni = 0; ni < 4; ni++) {
      int col = n0 + wn + ni * 16 + c;
      int h = col >> 6, d = col & 63;
#pragma unroll
      for (int r = 0; r < 4; r++) {
        int row = rowb + r;
        int b = row >> 11, sq = row & 2047;
        Qout[(((size_t)(b * 16 + h)) * 2048 + sq) * 64 + d] = f2bf(acc[mi][ni][r] * scale);
      }
    }
  }
}

// ---------------------------------------------------------------- K2: c = enc @ Wkva^T, LayerNorm, -> [16384,256] bf16
__global__ __launch_bounds__(256, 2) void k_cln(const unsigned short* __restrict__ E,
                                                const unsigned short* __restrict__ Wa,
                                                const float* __restrict__ g, const float* __restrict__ bb,
                                                unsigned short* __restrict__ Cout) {
  __shared__ __align__(16) short As[64 * 32];
  __shared__ __align__(16) short Bs[256 * 32];
  __shared__ float redS[4][64], redQ[4][64];
  __shared__ float gS[256], bS[256];
  const int K = 1024;
  int tid = threadIdx.x;
  int w = tid >> 6, lane = tid & 63, quad = lane >> 4, c = lane & 15;
  int m0 = blockIdx.x * 64;
  gS[tid] = g[tid];
  bS[tid] = bb[tid];
  f32x4 acc[4][4];
#pragma unroll
  for (int i = 0; i < 4; i++)
#pragma unroll
    for (int j = 0; j < 4; j++) acc[i][j] = zero4();

  for (int k0 = 0; k0 < K; k0 += 32) {
    {
      int bo = w * 1024 + lane * 16;
      int row = bo >> 6, col = (bo & 63) >> 1;
      GLDS16(E + (size_t)(m0 + row) * K + k0 + col, (char*)As + w * 1024);
    }
#pragma unroll
    for (int i = 0; i < 4; i++) {
      int seg = w * 4 + i;
      int bo = seg * 1024 + lane * 16;
      int row = bo >> 6, col = (bo & 63) >> 1;
      GLDS16(Wa + (size_t)row * K + k0 + col, (char*)Bs + seg * 1024);
    }
    __syncthreads();
    short8 af[4], bfr[4];
#pragma unroll
    for (int i = 0; i < 4; i++) {
      af[i] = *(const short8*)&As[(i * 16 + c) * 32 + quad * 8];
      bfr[i] = *(const short8*)&Bs[(w * 64 + i * 16 + c) * 32 + quad * 8];
    }
#pragma unroll
    for (int mi = 0; mi < 4; mi++)
#pragma unroll
      for (int ni = 0; ni < 4; ni++) acc[mi][ni] = MFMA16(af[mi], bfr[ni], acc[mi][ni]);
    __syncthreads();
  }
  float ps[4][4], pq[4][4];
#pragma unroll
  for (int mi = 0; mi < 4; mi++)
#pragma unroll
    for (int r = 0; r < 4; r++) {
      float s = 0.f, q = 0.f;
#pragma unroll
      for (int ni = 0; ni < 4; ni++) {
        float x = acc[mi][ni][r];
        s += x;
        q += x * x;
      }
      for (int m = 1; m < 16; m <<= 1) {
        s += __shfl_xor(s, m, 64);
        q += __shfl_xor(q, m, 64);
      }
      ps[mi][r] = s;
      pq[mi][r] = q;
    }
  if (c == 0) {
#pragma unroll
    for (int mi = 0; mi < 4; mi++)
#pragma unroll
      for (int r = 0; r < 4; r++) {
        int row = mi * 16 + quad * 4 + r;
        redS[w][row] = ps[mi][r];
        redQ[w][row] = pq[mi][r];
      }
  }
  __syncthreads();
  float muv[4][4], rsv[4][4];
#pragma unroll
  for (int mi = 0; mi < 4; mi++)
#pragma unroll
    for (int r = 0; r < 4; r++) {
      int row = mi * 16 + quad * 4 + r;
      float S = redS[0][row] + redS[1][row] + redS[2][row] + redS[3][row];
      float Q = redQ[0][row] + redQ[1][row] + redQ[2][row] + redQ[3][row];
      float mu = S * (1.f / 256.f);
      float var = Q * (1.f / 256.f) - mu * mu;
      muv[mi][r] = mu;
      rsv[mi][r] = rsqrtf(var + 1e-5f);
    }
#pragma unroll
  for (int mi = 0; mi < 4; mi++)
#pragma unroll
    for (int ni = 0; ni < 4; ni++) {
      int col = w * 64 + ni * 16 + c;
#pragma unroll
      for (int r = 0; r < 4; r++) {
        int row = m0 + mi * 16 + quad * 4 + r;
        float y = (acc[mi][ni][r] - muv[mi][r]) * rsv[mi][r] * gS[col] + bS[col];
        Cout[(size_t)row * 256 + col] = f2bf(y);
      }
    }
}

// ---------------------------------------------------------------- K3: kv = c_ln @ Wkvb^T -> K (B,H,SK,64), V^T (B,H,64,SK)
__global__ __launch_bounds__(256, 2) void k_kv(const unsigned short* __restrict__ A,
                                               const unsigned short* __restrict__ Bw,
                                               unsigned short* __restrict__ Kb,
                                               unsigned short* __restrict__ Vb) {
  __shared__ __align__(16) short As[128 * 32];
  __shared__ __align__(16) short Bs[128 * 32];
  const int K = 256;
  int tid = threadIdx.x;
  int w = tid >> 6, lane = tid & 63, quad = lane >> 4, c = lane & 15;
  int m0 = blockIdx.x * 128, n0 = blockIdx.y * 128;
  int wm = (w >> 1) * 64, wn = (w & 1) * 64;
  f32x4 acc[4][4];
#pragma unroll
  for (int i = 0; i < 4; i++)
#pragma unroll
    for (int j = 0; j < 4; j++) acc[i][j] = zero4();

  for (int k0 = 0; k0 < K; k0 += 32) {
#pragma unroll
    for (int i = 0; i < 2; i++) {
      int seg = w * 2 + i;
      int bo = seg * 1024 + lane * 16;
      int row = bo >> 6, col = (bo & 63) >> 1;
      GLDS16(A + (size_t)(m0 + row) * K + k0 + col, (char*)As + seg * 1024);
      GLDS16(Bw + (size_t)(n0 + row) * K + k0 + col, (char*)Bs + seg * 1024);
    }
    __syncthreads();
    short8 af[4], bfr[4];
#pragma unroll
    for (int i = 0; i < 4; i++) {
      af[i] = *(const short8*)&As[(wm + i * 16 + c) * 32 + quad * 8];
      bfr[i] = *(const short8*)&Bs[(wn + i * 16 + c) * 32 + quad * 8];
    }
#pragma unroll
    for (int mi = 0; mi < 4; mi++)
#pragma unroll
      for (int ni = 0; ni < 4; ni++) acc[mi][ni] = MFMA16(af[mi], bfr[ni], acc[mi][ni]);
    __syncthreads();
  }
#pragma unroll
  for (int mi = 0; mi < 4; mi++) {
    int rowb = m0 + wm + mi * 16 + quad * 4;
#pragma unroll
    for (int ni = 0; ni < 4; ni++) {
      int col = n0 + wn + ni * 16 + c;
      int h = col >> 7, rr = col & 127;
#pragma unroll
      for (int r = 0; r < 4; r++) {
        int row = rowb + r;
        int b = row >> 12, sk = row & 4095;
        float x = acc[mi][ni][r];
        if (rr < 64)
          Kb[(((size_t)(b * 16 + h)) * 4096 + sk) * 64 + rr] = f2bf(x);
        else
          Vb[(((size_t)(b * 16 + h)) * 64 + (rr - 64)) * 4096 + sk] = f2bf(x);
      }
    }
  }
}

// ---------------------------------------------------------------- K4: flash attention, split-K capable (NS = 1 or 2).
// 256 q-rows/block (4 waves x 64), 64-key tiles, 32 KiB LDS (KV 16 + P 16).
// Q fragments direct from global (no LDS). All LDS read addrs are base+imm
// (c-pure swizzles): K/V phys chunk = logical ^ (row&7); P phys chunk =
// logical ^ ((row>>1)&3). No running max; log2e/8 folded into Q.
// NS=2: writes unnormalized partial O (bf16) + l (fp32); k_comb merges.
template <int NS>
__global__ __launch_bounds__(256, 4) void k_attn(const unsigned short* __restrict__ Qb,
                                                 const unsigned short* __restrict__ Kb,
                                                 const unsigned short* __restrict__ Vb,
                                                 unsigned short* __restrict__ O0,
                                                 unsigned short* __restrict__ O1,
                                                 float* __restrict__ l0,
                                                 float* __restrict__ l1) {
  __shared__ __align__(16) short KVs[2 * 64 * 64];  // K tile | V^T tile, 16 KiB
  __shared__ __align__(16) short Ps[4][2048];       // per-wave P 64x32, 16 KiB
  int tid = threadIdx.x;
  int w = tid >> 6, lane = tid & 63, quad = lane >> 4, c = lane & 15;
  int r8 = lane >> 3, pc = lane & 7;
  int qt = blockIdx.x, ks = blockIdx.y, bh = blockIdx.z;
  const int ITERS = 64 / NS;

  const char* Kg = (const char*)Kb + (size_t)bh * 524288 + (size_t)ks * 262144;
  const char* Vg = (const char*)Vb + (size_t)bh * 524288 + (size_t)ks * 4096;
  const unsigned short* Qv = Qb + ((size_t)bh * 2048 + qt * 256 + w * 64) * 64 + c * 64 + quad * 8;

  // staging: waves 0,1 -> K (segs 0-7), waves 2,3 -> V (segs 8-15)
  const char* sg[4];
  int step = (w < 2) ? 8192 : 128;
#pragma unroll
  for (int i = 0; i < 4; i++) {
    int seg = w * 4 + i;
    if (w < 2) {
      int row = seg * 8 + r8;
      sg[i] = Kg + row * 128 + ((pc ^ r8) << 4);
    } else {
      int vrow = (seg - 8) * 8 + r8;
      sg[i] = Vg + (size_t)vrow * 8192 + ((pc ^ r8) << 4);
    }
  }

  // LDS read bases (all further addressing is +imm)
  int kb0 = c * 128 + ((quad ^ (c & 7)) << 4);
  int kb1 = c * 128 + (((quad + 4) ^ (c & 7)) << 4);
  const char* KsB0 = (const char*)KVs + kb0;
  const char* KsB1 = (const char*)KVs + kb1;
  const char* VsB0 = (const char*)KVs + 8192 + kb0;
  const char* VsB1 = (const char*)KVs + 8192 + kb1;
  int sP = (c >> 1) & 3;
  char* pw0 = (char*)Ps[w] + c * 64 + (quad & 1) * 8 + (((quad >> 1) ^ sP) << 4);
  char* pw1 = (char*)Ps[w] + c * 64 + (quad & 1) * 8 + ((((quad >> 1) + 2) ^ sP) << 4);
  const char* prB = (const char*)Ps[w] + c * 64 + ((quad ^ sP) << 4);

  // Q fragments in registers for the whole kernel (B-operand, dh halves)
  short8 qf[4][2];
#pragma unroll
  for (int nt = 0; nt < 4; nt++)
#pragma unroll
    for (int h = 0; h < 2; h++) qf[nt][h] = *(const short8*)(Qv + nt * 1024 + h * 32);

  f32x4 O[4][4];
  float lp[4] = {0.f, 0.f, 0.f, 0.f};
#pragma unroll
  for (int i = 0; i < 4; i++)
#pragma unroll
    for (int j = 0; j < 4; j++) O[i][j] = zero4();

  // stage tile 0
#pragma unroll
  for (int i = 0; i < 4; i++) {
    GLDS16(sg[i], (char*)KVs + (w * 4 + i) * 1024);
    sg[i] += step;
  }

  for (int kt = 0; kt < ITERS; kt++) {
    __syncthreads();  // drain GLDS for tile kt; protect P? (P is wave-private)
#pragma unroll
    for (int kk = 0; kk < 2; kk++) {
      // QK for 2 key-16 tiles (keys kk*32 .. kk*32+31), exp, pack, P write
#pragma unroll
      for (int mtl = 0; mtl < 2; mtl++) {
        int mt = kk * 2 + mtl;
        short8 kf0 = *(const short8*)(KsB0 + mt * 2048);
        short8 kf1 = *(const short8*)(KsB1 + mt * 2048);
        f32x4 s[4];
#pragma unroll
        for (int nt = 0; nt < 4; nt++) {
          s[nt] = MFMA16(kf0, qf[nt][0], zero4());
          s[nt] = MFMA16(kf1, qf[nt][1], s[nt]);
        }
#pragma unroll
        for (int nt = 0; nt < 4; nt++) {
          float p0 = __builtin_amdgcn_exp2f(s[nt][0]);
          float p1 = __builtin_amdgcn_exp2f(s[nt][1]);
          float p2 = __builtin_amdgcn_exp2f(s[nt][2]);
          float p3 = __builtin_amdgcn_exp2f(s[nt][3]);
          lp[nt] += (p0 + p1) + (p2 + p3);
          unsigned r0 = __float_as_uint(p0) + 0x8000u;
          unsigned r1 = __float_as_uint(p1) + 0x8000u;
          unsigned r2 = __float_as_uint(p2) + 0x8000u;
          unsigned r3 = __float_as_uint(p3) + 0x8000u;
          unsigned lo = __builtin_amdgcn_perm(r1, r0, 0x07060302u);
          unsigned hi = __builtin_amdgcn_perm(r3, r2, 0x07060302u);
          *(uint2*)((mtl ? pw1 : pw0) + nt * 1024) = make_uint2(lo, hi);
        }
      }
      // PV for this 32-key chunk
      {
        const char* VsB = kk ? VsB1 : VsB0;
        short8 vf[4];
#pragma unroll
        for (int dt = 0; dt < 4; dt++) vf[dt] = *(const short8*)(VsB + dt * 2048);
#pragma unroll
        for (int mo = 0; mo < 4; mo++) {
          short8 pf = *(const short8*)(prB + mo * 1024);
#pragma unroll
          for (int dt = 0; dt < 4; dt++) O[mo][dt] = MFMA16(pf, vf[dt], O[mo][dt]);
        }
      }
    }
    __syncthreads();  // all waves done reading KVs
    if (kt + 1 < ITERS) {
#pragma unroll
      for (int i = 0; i < 4; i++) {
        GLDS16(sg[i], (char*)KVs + (w * 4 + i) * 1024);
        sg[i] += step;
      }
    }
  }

  // reduce l across quads
#pragma unroll
  for (int nt = 0; nt < 4; nt++) {
    lp[nt] += __shfl_xor(lp[nt], 16, 64);
    lp[nt] += __shfl_xor(lp[nt], 32, 64);
  }
  int b = bh >> 4, h = bh & 15;
  if (NS == 1) {
#pragma unroll
    for (int mo = 0; mo < 4; mo++) {
#pragma unroll
      for (int r = 0; r < 4; r++) {
        float inv = __builtin_amdgcn_rcpf(__shfl(lp[mo], quad * 4 + r, 64));
        int sq = qt * 256 + w * 64 + mo * 16 + quad * 4 + r;
#pragma unroll
        for (int dt = 0; dt < 4; dt++)
          O0[((size_t)b * 2048 + sq) * 1024 + h * 64 + dt * 16 + c] = f2bf(O[mo][dt][r] * inv);
      }
    }
  } else {
    unsigned short* Op = ks ? O1 : O0;
    float* lq = ks ? l1 : l0;
#pragma unroll
    for (int mo = 0; mo < 4; mo++) {
#pragma unroll
      for (int r = 0; r < 4; r++) {
        int sq = qt * 256 + w * 64 + mo * 16 + quad * 4 + r;
#pragma unroll
        for (int dt = 0; dt < 4; dt++)
          Op[((size_t)b * 2048 + sq) * 1024 + h * 64 + dt * 16 + c] = f2bf(O[mo][dt][r]);
      }
    }
    float lsel = lp[0];
    if (quad == 1) lsel = lp[1];
    if (quad == 2) lsel = lp[2];
    if (quad == 3) lsel = lp[3];
    lq[(size_t)bh * 2048 + qt * 256 + w * 64 + quad * 16 + c] = lsel;
  }
}

// ---------------------------------------------------------------- combine split-K partials: A = (A+B)/(lA+lB), bf16 in-place
__global__ __launch_bounds__(256) void k_comb(unsigned short* __restrict__ A,
                                              const unsigned short* __restrict__ Bp,
                                              const float* __restrict__ lA,
                                              const float* __restrict__ lB) {
  int i = (blockIdx.x * 256 + threadIdx.x) * 4;
  int row = i >> 10, col = i & 1023;
  int bh = ((row >> 11) << 4) + (col >> 6);
  int li = bh * 2048 + (row & 2047);
  float inv = __builtin_amdgcn_rcpf(lA[li] + lB[li]);
  uint2 a = *(const uint2*)(A + i);
  uint2 bb = *(const uint2*)(Bp + i);
  float o0 = __uint_as_float(a.x << 16) + __uint_as_float(bb.x << 16);
  float o1 = __uint_as_float(a.x & 0xffff0000u) + __uint_as_float(bb.x & 0xffff0000u);
  float o2 = __uint_as_float(a.y << 16) + __uint_as_float(bb.y << 16);
  float o3 = __uint_as_float(a.y & 0xffff0000u) + __uint_as_float(bb.y & 0xffff0000u);
  unsigned lo = (unsigned)f2bf(o0 * inv) | ((unsigned)f2bf(o1 * inv) << 16);
  unsigned hi = (unsigned)f2bf(o2 * inv) | ((unsigned)f2bf(o3 * inv) << 16);
  *(uint2*)(A + i) = make_uint2(lo, hi);
}

// ---------------------------------------------------------------- K5: out = O @ Wout^T -> fp32
__global__ __launch_bounds__(256, 2) void k_out(const unsigned short* __restrict__ A,
                                                const unsigned short* __restrict__ Bw,
                                                float* __restrict__ Out) {
  __shared__ __align__(16) short As[128 * 32];
  __shared__ __align__(16) short Bs[128 * 32];
  const int K = 1024;
  int tid = threadIdx.x;
  int w = tid >> 6, lane = tid & 63, quad = lane >> 4, c = lane & 15;
  int m0 = blockIdx.x * 128, n0 = blockIdx.y * 128;
  int wm = (w >> 1) * 64, wn = (w & 1) * 64;
  f32x4 acc[4][4];
#pragma unroll
  for (int i = 0; i < 4; i++)
#pragma unroll
    for (int j = 0; j < 4; j++) acc[i][j] = zero4();

  for (int k0 = 0; k0 < K; k0 += 32) {
#pragma unroll
    for (int i = 0; i < 2; i++) {
      int seg = w * 2 + i;
      int bo = seg * 1024 + lane * 16;
      int row = bo >> 6, col = (bo & 63) >> 1;
      GLDS16(A + (size_t)(m0 + row) * K + k0 + col, (char*)As + seg * 1024);
      GLDS16(Bw + (size_t)(n0 + row) * K + k0 + col, (char*)Bs + seg * 1024);
    }
    __syncthreads();
    short8 af[4], bfr[4];
#pragma unroll
    for (int i = 0; i < 4; i++) {
      af[i] = *(const short8*)&As[(wm + i * 16 + c) * 32 + quad * 8];
      bfr[i] = *(const short8*)&Bs[(wn + i * 16 + c) * 32 + quad * 8];
    }
#pragma unroll
    for (int mi = 0; mi < 4; mi++)
#pragma unroll
      for (int ni = 0; ni < 4; ni++) acc[mi][ni] = MFMA16(af[mi], bfr[ni], acc[mi][ni]);
    __syncthreads();
  }
#pragma unroll
  for (int mi = 0; mi < 4; mi++) {
    int rowb = m0 + wm + mi * 16 + quad * 4;
#pragma unroll
    for (int ni = 0; ni < 4; ni++) {
      int col = n0 + wn + ni * 16 + c;
#pragma unroll
      for (int r = 0; r < 4; r++) Out[(size_t)(rowb + r) * 1024 + col] = acc[mi][ni][r];
    }
  }
}

// ---------------------------------------------------------------- launch
extern "C" void kernel_launch(void* const* d_in, const int* in_sizes, int n_in,
                              void* d_out, int out_size, void* d_ws, size_t ws_size,
                              hipStream_t stream) {
  const float* query = (const float*)d_in[0];
  const float* enc = (const float*)d_in[1];
  const float* Wq = (const float*)d_in[2];
  const float* Wkva = (const float*)d_in[3];
  const float* ln_g = (const float*)d_in[4];
  const float* ln_b = (const float*)d_in[5];
  const float* Wkvb = (const float*)d_in[6];
  const float* Wout = (const float*)d_in[7];
  if (ws_size < 81264640) return;

  char* ws = (char*)d_ws;
  bool split = ws_size >= 87031808;

  unsigned short *qbf, *ebf_v, *qproj, *cln, *oA, *oB, *wq_bf, *wa_bf, *wb_bf, *wo_bf;
  float *lA, *lB;
  if (split) {
    qbf = (unsigned short*)(ws + 0);          // 16 MiB: Q_in bf16 -> partial A -> final O
    ebf_v = (unsigned short*)(ws + 16777216); // 32 MiB: E bf16 -> V^T
    qproj = (unsigned short*)(ws + 50331648); // 16 MiB
    oB = (unsigned short*)(ws + 67108864);    // 16 MiB partial B (cln + wq/wa/wb parked inside pre-attn)
    cln = (unsigned short*)(ws + 67108864);   // 8 MiB (dead before B written)
    wq_bf = (unsigned short*)(ws + 75497472); // 2 MiB (dead before B)
    wa_bf = (unsigned short*)(ws + 77594624); // 0.5 MiB
    wb_bf = (unsigned short*)(ws + 78118912); // 1 MiB
    lA = (float*)(ws + 83886080);             // 0.5 MiB
    lB = (float*)(ws + 84410368);             // 0.5 MiB
    wo_bf = (unsigned short*)(ws + 84934656); // 2 MiB (survives attn)
    oA = qbf;
  } else {
    wq_bf = (unsigned short*)(ws + 0);
    wa_bf = (unsigned short*)(ws + 2097152);
    wb_bf = (unsigned short*)(ws + 2621440);
    wo_bf = (unsigned short*)(ws + 3670016);
    qproj = (unsigned short*)(ws + 5767168);
    cln = (unsigned short*)(ws + 22544384);
    ebf_v = (unsigned short*)(ws + 30932992);
    qbf = (unsigned short*)(ws + 64487424);
    oA = qbf;
    oB = qbf;
    lA = lB = (float*)(ws + 22544384);  // unused in NS=1
  }
  unsigned short* kbuf = (unsigned short*)d_out;  // K until final GEMM

  k_cast6<<<27392, 256, 0, stream>>>(enc, query, Wq, Wout, Wkvb, Wkva,
                                     ebf_v, qbf, wq_bf, wo_bf, wb_bf, wa_bf);

  k_qproj<<<dim3(64, 8), 256, 0, stream>>>(qbf, wq_bf, qproj);
  k_cln<<<256, 256, 0, stream>>>(ebf_v, wa_bf, ln_g, ln_b, cln);
  k_kv<<<dim3(128, 16), 256, 0, stream>>>(cln, wb_bf, kbuf, ebf_v);
  if (split) {
    k_attn<2><<<dim3(8, 2, 64), 256, 0, stream>>>(qproj, kbuf, ebf_v, oA, oB, lA, lB);
    k_comb<<<16384, 256, 0, stream>>>(oA, oB, lA, lB);
  } else {
    k_attn<1><<<dim3(8, 1, 64), 256, 0, stream>>>(qproj, kbuf, ebf_v, oA, oB, lA, lB);
  }
  k_out<<<dim3(64, 8), 256, 0, stream>>>(oA, wo_bf, (float*)d_out);
}

// Round 5
// 441.631 us; speedup vs baseline: 1.5193x; 1.5193x over previous
//
#include <hip/hip_runtime.h>

#define LOG2E 1.4426950408889634f

typedef __attribute__((ext_vector_type(8))) short short8;
typedef __attribute__((ext_vector_type(4))) float f32x4;

__device__ inline unsigned short f2bf(float f) {
  unsigned u = __float_as_uint(f);
  u += 0x7fffu + ((u >> 16) & 1u);
  return (unsigned short)(u >> 16);
}

#define MFMA16(a, b, c) __builtin_amdgcn_mfma_f32_16x16x32_bf16((a), (b), (c), 0, 0, 0)

#define GLDS16(gp, lp)                                                              \
  __builtin_amdgcn_global_load_lds((const __attribute__((address_space(1))) void*)(gp), \
                                   (__attribute__((address_space(3))) void*)(lp), 16, 0, 0)

__device__ inline f32x4 zero4() {
  f32x4 z = {0.f, 0.f, 0.f, 0.f};
  return z;
}

// ---------------------------------------------------------------- merged cast fp32 -> bf16 (all 6 arrays, 1 dispatch)
__global__ __launch_bounds__(256) void k_cast6(
    const float* __restrict__ e, const float* __restrict__ q, const float* __restrict__ wq,
    const float* __restrict__ wo, const float* __restrict__ wb, const float* __restrict__ wa,
    unsigned short* __restrict__ eo, unsigned short* __restrict__ qo, unsigned short* __restrict__ wqo,
    unsigned short* __restrict__ woo, unsigned short* __restrict__ wbo, unsigned short* __restrict__ wao) {
  int i = (blockIdx.x * 256 + threadIdx.x) * 4;
  const float* src;
  unsigned short* dst;
  int off;
  if (i < 16777216) { src = e; dst = eo; off = i; }
  else if (i < 25165824) { src = q; dst = qo; off = i - 16777216; }
  else if (i < 26214400) { src = wq; dst = wqo; off = i - 25165824; }
  else if (i < 27262976) { src = wo; dst = woo; off = i - 26214400; }
  else if (i < 27787264) { src = wb; dst = wbo; off = i - 27262976; }
  else { src = wa; dst = wao; off = i - 27787264; }
  float4 v = *(const float4*)(src + off);
  unsigned lo = (unsigned)f2bf(v.x) | ((unsigned)f2bf(v.y) << 16);
  unsigned hi = (unsigned)f2bf(v.z) | ((unsigned)f2bf(v.w) << 16);
  *(uint2*)(dst + off) = make_uint2(lo, hi);
}

// ---------------------------------------------------------------- K1: q = query @ Wq^T (scaled by log2e/8), -> (B,H,SQ,64) bf16
__global__ __launch_bounds__(256, 2) void k_qproj(const unsigned short* __restrict__ A,
                                                  const unsigned short* __restrict__ Bw,
                                                  unsigned short* __restrict__ Qout) {
  __shared__ __align__(16) short As[128 * 32];
  __shared__ __align__(16) short Bs[128 * 32];
  const int K = 1024;
  int tid = threadIdx.x;
  int w = tid >> 6, lane = tid & 63, quad = lane >> 4, c = lane & 15;
  int m0 = blockIdx.x * 128, n0 = blockIdx.y * 128;
  int wm = (w >> 1) * 64, wn = (w & 1) * 64;
  f32x4 acc[4][4];
#pragma unroll
  for (int i = 0; i < 4; i++)
#pragma unroll
    for (int j = 0; j < 4; j++) acc[i][j] = zero4();

  for (int k0 = 0; k0 < K; k0 += 32) {
#pragma unroll
    for (int i = 0; i < 2; i++) {
      int seg = w * 2 + i;
      int bo = seg * 1024 + lane * 16;
      int row = bo >> 6, col = (bo & 63) >> 1;
      GLDS16(A + (size_t)(m0 + row) * K + k0 + col, (char*)As + seg * 1024);
      GLDS16(Bw + (size_t)(n0 + row) * K + k0 + col, (char*)Bs + seg * 1024);
    }
    __syncthreads();
    short8 af[4], bfr[4];
#pragma unroll
    for (int i = 0; i < 4; i++) {
      af[i] = *(const short8*)&As[(wm + i * 16 + c) * 32 + quad * 8];
      bfr[i] = *(const short8*)&Bs[(wn + i * 16 + c) * 32 + quad * 8];
    }
#pragma unroll
    for (int mi = 0; mi < 4; mi++)
#pragma unroll
      for (int ni = 0; ni < 4; ni++) acc[mi][ni] = MFMA16(af[mi], bfr[ni], acc[mi][ni]);
    __syncthreads();
  }
  const float scale = 0.125f * LOG2E;
#pragma unroll
  for (int mi = 0; mi < 4; mi++) {
    int rowb = m0 + wm + mi * 16 + quad * 4;
#pragma unroll
    for (int ni = 0; ni < 4; ni++) {
      int col = n0 + wn + ni * 16 + c;
      int h = col >> 6, d = col & 63;
#pragma unroll
      for (int r = 0; r < 4; r++) {
        int row = rowb + r;
        int b = row >> 11, sq = row & 2047;
        Qout[(((size_t)(b * 16 + h)) * 2048 + sq) * 64 + d] = f2bf(acc[mi][ni][r] * scale);
      }
    }
  }
}

// ---------------------------------------------------------------- K2: c = enc @ Wkva^T, LayerNorm, -> [16384,256] bf16
__global__ __launch_bounds__(256, 2) void k_cln(const unsigned short* __restrict__ E,
                                                const unsigned short* __restrict__ Wa,
                                                const float* __restrict__ g, const float* __restrict__ bb,
                                                unsigned short* __restrict__ Cout) {
  __shared__ __align__(16) short As[64 * 32];
  __shared__ __align__(16) short Bs[256 * 32];
  __shared__ float redS[4][64], redQ[4][64];
  __shared__ float gS[256], bS[256];
  const int K = 1024;
  int tid = threadIdx.x;
  int w = tid >> 6, lane = tid & 63, quad = lane >> 4, c = lane & 15;
  int m0 = blockIdx.x * 64;
  gS[tid] = g[tid];
  bS[tid] = bb[tid];
  f32x4 acc[4][4];
#pragma unroll
  for (int i = 0; i < 4; i++)
#pragma unroll
    for (int j = 0; j < 4; j++) acc[i][j] = zero4();

  for (int k0 = 0; k0 < K; k0 += 32) {
    {
      int bo = w * 1024 + lane * 16;
      int row = bo >> 6, col = (bo & 63) >> 1;
      GLDS16(E + (size_t)(m0 + row) * K + k0 + col, (char*)As + w * 1024);
    }
#pragma unroll
    for (int i = 0; i < 4; i++) {
      int seg = w * 4 + i;
      int bo = seg * 1024 + lane * 16;
      int row = bo >> 6, col = (bo & 63) >> 1;
      GLDS16(Wa + (size_t)row * K + k0 + col, (char*)Bs + seg * 1024);
    }
    __syncthreads();
    short8 af[4], bfr[4];
#pragma unroll
    for (int i = 0; i < 4; i++) {
      af[i] = *(const short8*)&As[(i * 16 + c) * 32 + quad * 8];
      bfr[i] = *(const short8*)&Bs[(w * 64 + i * 16 + c) * 32 + quad * 8];
    }
#pragma unroll
    for (int mi = 0; mi < 4; mi++)
#pragma unroll
      for (int ni = 0; ni < 4; ni++) acc[mi][ni] = MFMA16(af[mi], bfr[ni], acc[mi][ni]);
    __syncthreads();
  }
  float ps[4][4], pq[4][4];
#pragma unroll
  for (int mi = 0; mi < 4; mi++)
#pragma unroll
    for (int r = 0; r < 4; r++) {
      float s = 0.f, q = 0.f;
#pragma unroll
      for (int ni = 0; ni < 4; ni++) {
        float x = acc[mi][ni][r];
        s += x;
        q += x * x;
      }
      for (int m = 1; m < 16; m <<= 1) {
        s += __shfl_xor(s, m, 64);
        q += __shfl_xor(q, m, 64);
      }
      ps[mi][r] = s;
      pq[mi][r] = q;
    }
  if (c == 0) {
#pragma unroll
    for (int mi = 0; mi < 4; mi++)
#pragma unroll
      for (int r = 0; r < 4; r++) {
        int row = mi * 16 + quad * 4 + r;
        redS[w][row] = ps[mi][r];
        redQ[w][row] = pq[mi][r];
      }
  }
  __syncthreads();
  float muv[4][4], rsv[4][4];
#pragma unroll
  for (int mi = 0; mi < 4; mi++)
#pragma unroll
    for (int r = 0; r < 4; r++) {
      int row = mi * 16 + quad * 4 + r;
      float S = redS[0][row] + redS[1][row] + redS[2][row] + redS[3][row];
      float Q = redQ[0][row] + redQ[1][row] + redQ[2][row] + redQ[3][row];
      float mu = S * (1.f / 256.f);
      float var = Q * (1.f / 256.f) - mu * mu;
      muv[mi][r] = mu;
      rsv[mi][r] = rsqrtf(var + 1e-5f);
    }
#pragma unroll
  for (int mi = 0; mi < 4; mi++)
#pragma unroll
    for (int ni = 0; ni < 4; ni++) {
      int col = w * 64 + ni * 16 + c;
#pragma unroll
      for (int r = 0; r < 4; r++) {
        int row = m0 + mi * 16 + quad * 4 + r;
        float y = (acc[mi][ni][r] - muv[mi][r]) * rsv[mi][r] * gS[col] + bS[col];
        Cout[(size_t)row * 256 + col] = f2bf(y);
      }
    }
}

// ---------------------------------------------------------------- K3: kv = c_ln @ Wkvb^T -> K (B,H,SK,64), V^T (B,H,64,SK)
__global__ __launch_bounds__(256, 2) void k_kv(const unsigned short* __restrict__ A,
                                               const unsigned short* __restrict__ Bw,
                                               unsigned short* __restrict__ Kb,
                                               unsigned short* __restrict__ Vb) {
  __shared__ __align__(16) short As[128 * 32];
  __shared__ __align__(16) short Bs[128 * 32];
  const int K = 256;
  int tid = threadIdx.x;
  int w = tid >> 6, lane = tid & 63, quad = lane >> 4, c = lane & 15;
  int m0 = blockIdx.x * 128, n0 = blockIdx.y * 128;
  int wm = (w >> 1) * 64, wn = (w & 1) * 64;
  f32x4 acc[4][4];
#pragma unroll
  for (int i = 0; i < 4; i++)
#pragma unroll
    for (int j = 0; j < 4; j++) acc[i][j] = zero4();

  for (int k0 = 0; k0 < K; k0 += 32) {
#pragma unroll
    for (int i = 0; i < 2; i++) {
      int seg = w * 2 + i;
      int bo = seg * 1024 + lane * 16;
      int row = bo >> 6, col = (bo & 63) >> 1;
      GLDS16(A + (size_t)(m0 + row) * K + k0 + col, (char*)As + seg * 1024);
      GLDS16(Bw + (size_t)(n0 + row) * K + k0 + col, (char*)Bs + seg * 1024);
    }
    __syncthreads();
    short8 af[4], bfr[4];
#pragma unroll
    for (int i = 0; i < 4; i++) {
      af[i] = *(const short8*)&As[(wm + i * 16 + c) * 32 + quad * 8];
      bfr[i] = *(const short8*)&Bs[(wn + i * 16 + c) * 32 + quad * 8];
    }
#pragma unroll
    for (int mi = 0; mi < 4; mi++)
#pragma unroll
      for (int ni = 0; ni < 4; ni++) acc[mi][ni] = MFMA16(af[mi], bfr[ni], acc[mi][ni]);
    __syncthreads();
  }
#pragma unroll
  for (int mi = 0; mi < 4; mi++) {
    int rowb = m0 + wm + mi * 16 + quad * 4;
#pragma unroll
    for (int ni = 0; ni < 4; ni++) {
      int col = n0 + wn + ni * 16 + c;
      int h = col >> 7, rr = col & 127;
#pragma unroll
      for (int r = 0; r < 4; r++) {
        int row = rowb + r;
        int b = row >> 12, sk = row & 4095;
        float x = acc[mi][ni][r];
        if (rr < 64)
          Kb[(((size_t)(b * 16 + h)) * 4096 + sk) * 64 + rr] = f2bf(x);
        else
          Vb[(((size_t)(b * 16 + h)) * 64 + (rr - 64)) * 4096 + sk] = f2bf(x);
      }
    }
  }
}

// ---------------------------------------------------------------- K4: flash attention, 32 q-rows/wave, 4 blocks/CU.
// Block = 128 q-rows (4 waves x 32), grid (16 qt, 64 bh) = 1024 blocks = 4/CU
// = 16 waves/CU. Register budget fits launch_bounds(256,4): O[2][4]=32 acc,
// qf[2][2]=16, ~63 misc arch -> ~111 < 128 (R4's spill fixed by shrinking the
// per-wave tile, NOT by relaxing bounds). LDS 32 KiB: KV 16 + P (32x64/wave) 16.
// S^T = K Q^T; no running max (scores bounded; log2e/8 folded into Q); all LDS
// read/write addrs are base+imm with c-pure XOR swizzles (conflict-free).
__global__ __launch_bounds__(256, 4) void k_attn(const unsigned short* __restrict__ Qb,
                                                 const unsigned short* __restrict__ Kb,
                                                 const unsigned short* __restrict__ Vb,
                                                 unsigned short* __restrict__ Ob) {
  __shared__ __align__(16) short KVs[2 * 64 * 64];  // K tile | V^T tile, 16 KiB
  __shared__ __align__(16) short Ps[4][2048];       // per-wave P 32x64, 16 KiB
  int tid = threadIdx.x;
  int w = tid >> 6, lane = tid & 63, quad = lane >> 4, c = lane & 15;
  int r8 = lane >> 3, pc = lane & 7;
  int qt = blockIdx.x, bh = blockIdx.y;

  const char* Kg = (const char*)Kb + (size_t)bh * 524288;
  const char* Vg = (const char*)Vb + (size_t)bh * 524288;
  const unsigned short* Qv = Qb + ((size_t)bh * 2048 + qt * 128 + w * 32) * 64 + c * 64 + quad * 8;

  // staging: waves 0,1 -> K rows (segs 0-7), waves 2,3 -> V^T rows (segs 8-15)
  const char* sg[4];
  int step = (w < 2) ? 8192 : 128;
#pragma unroll
  for (int i = 0; i < 4; i++) {
    int seg = w * 4 + i;
    if (w < 2) {
      int row = seg * 8 + r8;
      sg[i] = Kg + row * 128 + ((pc ^ r8) << 4);
    } else {
      int vrow = (seg - 8) * 8 + r8;
      sg[i] = Vg + (size_t)vrow * 8192 + ((pc ^ r8) << 4);
    }
  }

  int c7 = c & 7;
  int kb0 = c * 128 + ((quad ^ c7) << 4);
  int kb1 = c * 128 + (((quad + 4) ^ c7) << 4);
  const char* KsB0 = (const char*)KVs + kb0;
  const char* KsB1 = (const char*)KVs + kb1;
  const char* VsB0 = (const char*)KVs + 8192 + kb0;
  const char* VsB1 = (const char*)KVs + 8192 + kb1;
  // P write ptrs (one per 16-key tile mt): row=c (nt adds +2048 imm),
  // phys chunk = (mt*2 + (quad>>1)) ^ (c&7), sub-offset (quad&1)*8
  char* pwm[4];
#pragma unroll
  for (int mt = 0; mt < 4; mt++)
    pwm[mt] = (char*)Ps[w] + c * 128 + (quad & 1) * 8 + ((((mt * 2) ^ (quad >> 1) ^ c7)) << 4);
  // P read bases (A-operand): chunk = (kk*4+quad) ^ (c&7)
  const char* pr0 = (const char*)Ps[w] + c * 128 + ((quad ^ c7) << 4);
  const char* pr1 = (const char*)Ps[w] + c * 128 + (((quad + 4) ^ c7) << 4);

  // Q fragments in registers for the whole kernel (B-operand, 2 row-tiles x 2 dh-halves)
  short8 qf[2][2];
#pragma unroll
  for (int nt = 0; nt < 2; nt++)
#pragma unroll
    for (int h = 0; h < 2; h++) qf[nt][h] = *(const short8*)(Qv + nt * 1024 + h * 32);

  f32x4 O[2][4];
  float lp[2] = {0.f, 0.f};
#pragma unroll
  for (int i = 0; i < 2; i++)
#pragma unroll
    for (int j = 0; j < 4; j++) O[i][j] = zero4();

  // stage tile 0
#pragma unroll
  for (int i = 0; i < 4; i++) {
    GLDS16(sg[i], (char*)KVs + (w * 4 + i) * 1024);
    sg[i] += step;
  }

  for (int kt = 0; kt < 64; kt++) {
    __syncthreads();  // drain GLDS for tile kt
    // S^T = K Q^T per 16-key tile; exp2; packed b64 P-writes
#pragma unroll
    for (int mt = 0; mt < 4; mt++) {
      short8 kf0 = *(const short8*)(KsB0 + mt * 2048);
      short8 kf1 = *(const short8*)(KsB1 + mt * 2048);
      f32x4 s0 = MFMA16(kf0, qf[0][0], zero4());
      s0 = MFMA16(kf1, qf[0][1], s0);
      f32x4 s1 = MFMA16(kf0, qf[1][0], zero4());
      s1 = MFMA16(kf1, qf[1][1], s1);
#pragma unroll
      for (int nt = 0; nt < 2; nt++) {
        f32x4 s = nt ? s1 : s0;
        float p0 = __builtin_amdgcn_exp2f(s[0]);
        float p1 = __builtin_amdgcn_exp2f(s[1]);
        float p2 = __builtin_amdgcn_exp2f(s[2]);
        float p3 = __builtin_amdgcn_exp2f(s[3]);
        lp[nt] += (p0 + p1) + (p2 + p3);
        unsigned r0 = __float_as_uint(p0) + 0x8000u;
        unsigned r1 = __float_as_uint(p1) + 0x8000u;
        unsigned r2 = __float_as_uint(p2) + 0x8000u;
        unsigned r3 = __float_as_uint(p3) + 0x8000u;
        unsigned lo = __builtin_amdgcn_perm(r1, r0, 0x07060302u);
        unsigned hi = __builtin_amdgcn_perm(r3, r2, 0x07060302u);
        *(uint2*)(pwm[mt] + nt * 2048) = make_uint2(lo, hi);
      }
    }
    // O += P V (P wave-private; same-wave LDS write->read ordered by lgkmcnt)
#pragma unroll
    for (int kk = 0; kk < 2; kk++) {
      const char* VsB = kk ? VsB1 : VsB0;
      const char* pr = kk ? pr1 : pr0;
      short8 vf[4];
#pragma unroll
      for (int dt = 0; dt < 4; dt++) vf[dt] = *(const short8*)(VsB + dt * 2048);
#pragma unroll
      for (int mo = 0; mo < 2; mo++) {
        short8 pf = *(const short8*)(pr + mo * 2048);
#pragma unroll
        for (int dt = 0; dt < 4; dt++) O[mo][dt] = MFMA16(pf, vf[dt], O[mo][dt]);
      }
    }
    __syncthreads();  // all waves done reading KVs
    if (kt < 63) {
#pragma unroll
      for (int i = 0; i < 4; i++) {
        GLDS16(sg[i], (char*)KVs + (w * 4 + i) * 1024);
        sg[i] += step;
      }
    }
  }

  // reduce l across quads
#pragma unroll
  for (int nt = 0; nt < 2; nt++) {
    lp[nt] += __shfl_xor(lp[nt], 16, 64);
    lp[nt] += __shfl_xor(lp[nt], 32, 64);
  }
  int b = bh >> 4, h = bh & 15;
#pragma unroll
  for (int mo = 0; mo < 2; mo++) {
#pragma unroll
    for (int r = 0; r < 4; r++) {
      float inv = __builtin_amdgcn_rcpf(__shfl(lp[mo], quad * 4 + r, 64));
      int sq = qt * 128 + w * 32 + mo * 16 + quad * 4 + r;
#pragma unroll
      for (int dt = 0; dt < 4; dt++)
        Ob[((size_t)b * 2048 + sq) * 1024 + h * 64 + dt * 16 + c] = f2bf(O[mo][dt][r] * inv);
    }
  }
}

// ---------------------------------------------------------------- K5: out = O @ Wout^T -> fp32
__global__ __launch_bounds__(256, 2) void k_out(const unsigned short* __restrict__ A,
                                                const unsigned short* __restrict__ Bw,
                                                float* __restrict__ Out) {
  __shared__ __align__(16) short As[128 * 32];
  __shared__ __align__(16) short Bs[128 * 32];
  const int K = 1024;
  int tid = threadIdx.x;
  int w = tid >> 6, lane = tid & 63, quad = lane >> 4, c = lane & 15;
  int m0 = blockIdx.x * 128, n0 = blockIdx.y * 128;
  int wm = (w >> 1) * 64, wn = (w & 1) * 64;
  f32x4 acc[4][4];
#pragma unroll
  for (int i = 0; i < 4; i++)
#pragma unroll
    for (int j = 0; j < 4; j++) acc[i][j] = zero4();

  for (int k0 = 0; k0 < K; k0 += 32) {
#pragma unroll
    for (int i = 0; i < 2; i++) {
      int seg = w * 2 + i;
      int bo = seg * 1024 + lane * 16;
      int row = bo >> 6, col = (bo & 63) >> 1;
      GLDS16(A + (size_t)(m0 + row) * K + k0 + col, (char*)As + seg * 1024);
      GLDS16(Bw + (size_t)(n0 + row) * K + k0 + col, (char*)Bs + seg * 1024);
    }
    __syncthreads();
    short8 af[4], bfr[4];
#pragma unroll
    for (int i = 0; i < 4; i++) {
      af[i] = *(const short8*)&As[(wm + i * 16 + c) * 32 + quad * 8];
      bfr[i] = *(const short8*)&Bs[(wn + i * 16 + c) * 32 + quad * 8];
    }
#pragma unroll
    for (int mi = 0; mi < 4; mi++)
#pragma unroll
      for (int ni = 0; ni < 4; ni++) acc[mi][ni] = MFMA16(af[mi], bfr[ni], acc[mi][ni]);
    __syncthreads();
  }
#pragma unroll
  for (int mi = 0; mi < 4; mi++) {
    int rowb = m0 + wm + mi * 16 + quad * 4;
#pragma unroll
    for (int ni = 0; ni < 4; ni++) {
      int col = n0 + wn + ni * 16 + c;
#pragma unroll
      for (int r = 0; r < 4; r++) Out[(size_t)(rowb + r) * 1024 + col] = acc[mi][ni][r];
    }
  }
}

// ---------------------------------------------------------------- launch
extern "C" void kernel_launch(void* const* d_in, const int* in_sizes, int n_in,
                              void* d_out, int out_size, void* d_ws, size_t ws_size,
                              hipStream_t stream) {
  const float* query = (const float*)d_in[0];
  const float* enc = (const float*)d_in[1];
  const float* Wq = (const float*)d_in[2];
  const float* Wkva = (const float*)d_in[3];
  const float* ln_g = (const float*)d_in[4];
  const float* ln_b = (const float*)d_in[5];
  const float* Wkvb = (const float*)d_in[6];
  const float* Wout = (const float*)d_in[7];
  if (ws_size < 81264640) return;  // need ~77.5 MB scratch

  char* ws = (char*)d_ws;
  unsigned short* wq_bf = (unsigned short*)(ws + 0);         // 2 MB
  unsigned short* wa_bf = (unsigned short*)(ws + 2097152);   // 512 KB
  unsigned short* wb_bf = (unsigned short*)(ws + 2621440);   // 1 MB
  unsigned short* wo_bf = (unsigned short*)(ws + 3670016);   // 2 MB
  unsigned short* qproj = (unsigned short*)(ws + 5767168);   // 16 MB (B,H,SQ,64)
  unsigned short* cln = (unsigned short*)(ws + 22544384);    // 8 MB
  unsigned short* ebf_v = (unsigned short*)(ws + 30932992);  // 32 MB: E_bf, then V^T
  unsigned short* qin_o = (unsigned short*)(ws + 64487424);  // 16 MB: Q_in bf16, then O
  unsigned short* kbuf = (unsigned short*)d_out;             // 32 MB: K until final GEMM

  k_cast6<<<27392, 256, 0, stream>>>(enc, query, Wq, Wout, Wkvb, Wkva,
                                     ebf_v, qin_o, wq_bf, wo_bf, wb_bf, wa_bf);

  k_qproj<<<dim3(64, 8), 256, 0, stream>>>(qin_o, wq_bf, qproj);
  k_cln<<<256, 256, 0, stream>>>(ebf_v, wa_bf, ln_g, ln_b, cln);
  k_kv<<<dim3(128, 16), 256, 0, stream>>>(cln, wb_bf, kbuf, ebf_v);
  k_attn<<<dim3(16, 64), 256, 0, stream>>>(qproj, kbuf, ebf_v, qin_o);
  k_out<<<dim3(64, 8), 256, 0, stream>>>(qin_o, wo_bf, (float*)d_out);
}